// Round 11
// baseline (629.756 us; speedup 1.0000x reference)
//
#include <hip/hip_runtime.h>
#include <hip/hip_bf16.h>

#define Nn 100000
#define Ee 1600000
#define Hh 128
#define Gg 1000
#define EPSb 1e-5f

#define SCAN_CHUNK 1024
#define NB_SCAN 98          // ceil(100000/1024)
#define AGG_BLOCKS 2048
#define NWAVES (AGG_BLOCKS * 4)   // 8192
#define GEMM_BLOCKS 782     // ceil(100000/128)

typedef unsigned int uint;
typedef short short8 __attribute__((ext_vector_type(8)));
typedef float floatx4 __attribute__((ext_vector_type(4)));

// round-to-nearest-even f32 -> bf16 (as low 16 bits of return)
static __device__ __forceinline__ uint bf16rne(float f) {
    uint u = __float_as_uint(f);
    return (u + 0x7fffu + ((u >> 16) & 1u)) >> 16;
}
static __device__ __forceinline__ float bflo(uint u) { return __uint_as_float(u << 16); }
static __device__ __forceinline__ float bfhi(uint u) { return __uint_as_float(u & 0xffff0000u); }

// ---------------- graph preprocessing ----------------
// deg/cursor/colsum zeroed by one hipMemsetAsync; deg = in-degree only,
// the self-loop +1 is folded into the scans.
// dinv factorization: h' rows are pre-scaled by dinv[src] in the GEMM
// epilogue; agg applies dinv[d] once per node. adjacency = src index only.

__global__ void k_deg(const int* __restrict__ dst, int* __restrict__ deg) {
    int i = blockIdx.x * blockDim.x + threadIdx.x;
    if (i < Ee) atomicAdd(&deg[dst[i]], 1);
}

__global__ void k_scan1(const int* __restrict__ deg, int* __restrict__ bsum) {
    __shared__ int ls[256];
    int t = threadIdx.x;
    int base = blockIdx.x * SCAN_CHUNK + t * 4;
    int s = 0;
#pragma unroll
    for (int j = 0; j < 4; ++j) { int i = base + j; if (i < Nn) s += deg[i] + 1; }
    ls[t] = s;
    __syncthreads();
    for (int off = 128; off; off >>= 1) {
        if (t < off) ls[t] += ls[t + off];
        __syncthreads();
    }
    if (t == 0) bsum[blockIdx.x] = ls[0];
}

// scan3: in-block scan of the 98 block sums, per-block exclusive scan over
// deg+1, emits offs and dinv.
__global__ void k_scan3(const int* __restrict__ deg, const int* __restrict__ bsum,
                        int* __restrict__ offs, float* __restrict__ dinv) {
    __shared__ int ls[256];
    __shared__ int bs[128];
    int t = threadIdx.x;
    if (t < 128) bs[t] = (t < NB_SCAN) ? bsum[t] : 0;
    int base = blockIdx.x * SCAN_CHUNK + t * 4;
    int d[4]; int s = 0;
#pragma unroll
    for (int j = 0; j < 4; ++j) {
        int i = base + j;
        d[j] = (i < Nn) ? deg[i] + 1 : 0;
        s += d[j];
    }
    ls[t] = s;
    __syncthreads();
    for (int off = 1; off < 128; off <<= 1) {
        int u = (t >= off && t < 128) ? bs[t - off] : 0;
        __syncthreads();
        if (t < 128) bs[t] += u;
        __syncthreads();
    }
    for (int off = 1; off < 256; off <<= 1) {
        int u = (t >= off) ? ls[t - off] : 0;
        __syncthreads();
        ls[t] += u;
        __syncthreads();
    }
    int blockBase = (blockIdx.x == 0) ? 0 : bs[blockIdx.x - 1];
    int run = blockBase + ls[t] - s;   // exclusive prefix for this thread
#pragma unroll
    for (int j = 0; j < 4; ++j) {
        int i = base + j;
        if (i < Nn) {
            offs[i] = run;
            dinv[i] = rsqrtf((float)d[j]);
        }
        run += d[j];
    }
    if (blockIdx.x == 0 && t == 0) offs[Nn] = Ee + Nn;
}

// fill: src-only adjacency (4B/edge) -- no dinv gathers, no weight calc.
__global__ void k_fill(const int* __restrict__ src, const int* __restrict__ dst,
                       const int* __restrict__ offs, int* __restrict__ cursor,
                       int* __restrict__ adj) {
    int i = blockIdx.x * blockDim.x + threadIdx.x;
    if (i >= Ee + Nn) return;
    int s, d;
    if (i < Ee) { s = src[i]; d = dst[i]; }
    else        { s = d = i - Ee; }
    int pos = offs[d] + atomicAdd(&cursor[d], 1);
    adj[pos] = s;
}

// ------- W conversion (all 3 layers): Wt[l][n][k/2] = bf16(W[k][n],W[k+1][n]) --

__global__ void k_wconv3(const float* __restrict__ W1, const float* __restrict__ W2,
                         const float* __restrict__ W3, uint* __restrict__ Wt) {
    int idx = blockIdx.x * blockDim.x + threadIdx.x;   // 3*8192
    if (idx >= 3 * 8192) return;
    const float* W = (idx < 8192) ? W1 : ((idx < 16384) ? W2 : W3);
    int k = idx & 8191;
    int n = k >> 6, ku = k & 63;
    uint lo = bf16rne(W[(size_t)(2 * ku) * 128 + n]);
    uint hi = bf16rne(W[(size_t)(2 * ku + 1) * 128 + n]);
    Wt[(size_t)(idx >> 13) * 8192 + n * 64 + ku] = lo | (hi << 16);
}

// ---------------- MFMA GEMM: tmp(bf16) = dinv[node] * (act(in) @ W) --------
// mode 0: in = fp32 x (row-major), identity activation.
// mode 1: in = row-major packed-bf16 agg; activation = relu(bn(v)), BN affine
// computed in-block from colsum + gamma + beta.
// Epilogue scales each output row by dinv[node] (GCN weight factorization).

__global__ __launch_bounds__(256) void k_gemm(
    const float* __restrict__ inf, const uint* __restrict__ inb,
    const uint* __restrict__ Wtp, const float* __restrict__ dinv,
    const float* __restrict__ cs, const float* __restrict__ gg,
    const float* __restrict__ be,
    uint* __restrict__ outb, int mode) {
    __shared__ uint XT[128][64];
    __shared__ uint WT[128][64];
    __shared__ float scsh[256];   // sc[128], sh[128]
    int t = threadIdx.x;
    int rowBase = blockIdx.x * 128;
    int r = t >> 1, half = t & 1;

    if (mode) {
        if (t < 128) {
            float s = cs[t], q = cs[128 + t];
            float m = s * (1.0f / Nn);
            float var = q * (1.0f / Nn) - m * m;
            float istd = rsqrtf(var + EPSb);
            float sc = istd * gg[t];
            scsh[t] = sc;
            scsh[128 + t] = fmaf(-m, sc, be[t]);
        }
        __syncthreads();
    }

    {   // stage activations
        int gr = rowBase + r;
        int grc = gr < Nn ? gr : Nn - 1;
        if (mode == 0) {
            const float* sp = inf + (size_t)grc * 128 + half * 64;
#pragma unroll
            for (int q = 0; q < 8; ++q) {
                float4 v0 = *(const float4*)(sp + q * 8);
                float4 v1 = *(const float4*)(sp + q * 8 + 4);
                uint4 o;
                o.x = bf16rne(v0.x) | (bf16rne(v0.y) << 16);
                o.y = bf16rne(v0.z) | (bf16rne(v0.w) << 16);
                o.z = bf16rne(v1.x) | (bf16rne(v1.y) << 16);
                o.w = bf16rne(v1.z) | (bf16rne(v1.w) << 16);
                int g = half * 8 + q;
                *(uint4*)&XT[r][(g ^ (r & 7)) << 2] = o;
            }
        } else {
            const uint* sp = inb + (size_t)grc * 64 + half * 32;
#pragma unroll
            for (int q = 0; q < 8; ++q) {
                uint4 v = *(const uint4*)(sp + q * 4);
                int fb = half * 64 + q * 8;
                float av[8] = {bflo(v.x), bfhi(v.x), bflo(v.y), bfhi(v.y),
                               bflo(v.z), bfhi(v.z), bflo(v.w), bfhi(v.w)};
                uint o[4];
#pragma unroll
                for (int k2 = 0; k2 < 4; ++k2) {
                    float lo = fmaxf(fmaf(av[2 * k2], scsh[fb + 2 * k2],
                                          scsh[128 + fb + 2 * k2]), 0.f);
                    float hi = fmaxf(fmaf(av[2 * k2 + 1], scsh[fb + 2 * k2 + 1],
                                          scsh[128 + fb + 2 * k2 + 1]), 0.f);
                    o[k2] = bf16rne(lo) | (bf16rne(hi) << 16);
                }
                uint4 ov = make_uint4(o[0], o[1], o[2], o[3]);
                int g = half * 8 + q;
                *(uint4*)&XT[r][(g ^ (r & 7)) << 2] = ov;
            }
        }
    }
    {   // stage W^T (already packed bf16)
        const uint* sp = Wtp + (size_t)r * 64 + half * 32;
#pragma unroll
        for (int q = 0; q < 8; ++q) {
            uint4 v = *(const uint4*)(sp + q * 4);
            int g = half * 8 + q;
            *(uint4*)&WT[r][(g ^ (r & 7)) << 2] = v;
        }
    }
    __syncthreads();

    int l = t & 63, w = t >> 6;
    int nb = (w >> 1) * 64;       // node-tile base
    int fb2 = (w & 1) * 64;       // feature-tile base
    int lr = l & 15, lk = l >> 4;
    floatx4 zero = {0.f, 0.f, 0.f, 0.f};
    floatx4 acc[4][4];
#pragma unroll
    for (int mi = 0; mi < 4; ++mi)
#pragma unroll
        for (int ni = 0; ni < 4; ++ni) acc[mi][ni] = zero;

#pragma unroll
    for (int kc = 0; kc < 4; ++kc) {
        short8 xf[4], wf[4];
        int g = kc * 4 + lk;
#pragma unroll
        for (int mi = 0; mi < 4; ++mi) {
            int rr = nb + mi * 16 + lr;
            xf[mi] = *(const short8*)&XT[rr][(g ^ (rr & 7)) << 2];
        }
#pragma unroll
        for (int ni = 0; ni < 4; ++ni) {
            int rr = fb2 + ni * 16 + lr;
            wf[ni] = *(const short8*)&WT[rr][(g ^ (rr & 7)) << 2];
        }
#pragma unroll
        for (int mi = 0; mi < 4; ++mi)
#pragma unroll
            for (int ni = 0; ni < 4; ++ni)
                acc[mi][ni] = __builtin_amdgcn_mfma_f32_16x16x32_bf16(
                    wf[ni], xf[mi], acc[mi][ni], 0, 0, 0);
    }

    // epilogue: D col(lane&15)=node, row((lane>>4)*4+reg)=feature; scale by dinv
#pragma unroll
    for (int mi = 0; mi < 4; ++mi) {
        int node = rowBase + nb + mi * 16 + lr;
        if (node < Nn) {
            float dv = dinv[node];
            uint* op = outb + (size_t)node * 64;
#pragma unroll
            for (int ni = 0; ni < 4; ++ni) {
                int fo = fb2 + ni * 16 + lk * 4;
                uint2 o;
                o.x = bf16rne(acc[mi][ni][0] * dv) | (bf16rne(acc[mi][ni][1] * dv) << 16);
                o.y = bf16rne(acc[mi][ni][2] * dv) | (bf16rne(acc[mi][ni][3] * dv) << 16);
                *(uint2*)(op + (fo >> 1)) = o;
            }
        }
    }
}

// ------- aggregation: agg[d] = dinv[d]*sum_e h'[src] + bias; BN partials ----
// Round-3/7-proven loop shape; src-only adjacency, no per-edge weights.

__global__ __launch_bounds__(256) void k_agg(
    const uint* __restrict__ h32, const int* __restrict__ offs,
    const int* __restrict__ adj, const float* __restrict__ dinv,
    const float* __restrict__ bias, uint* __restrict__ agg,
    float* __restrict__ colsum) {
    __shared__ float ls[256];
    int tid = threadIdx.x;
    ls[tid] = 0.f;
    __syncthreads();
    int lane = tid & 63;
    int gw = blockIdx.x * 4 + (tid >> 6);
    int nw = NWAVES;
    int c0 = lane * 2;
    float b0 = bias[c0], b1 = bias[c0 + 1];
    float ps0 = 0.f, pq0 = 0.f, ps1 = 0.f, pq1 = 0.f;
    for (int d = gw; d < Nn; d += nw) {
        int beg = offs[d], end = offs[d + 1];
        float dvd = dinv[d];
        float a0 = 0.f, a1 = 0.f;
        int i = beg;
        for (; i + 8 <= end; i += 8) {
            int e[8];
#pragma unroll
            for (int j = 0; j < 8; ++j) e[j] = adj[i + j];
            uint hv[8];
#pragma unroll
            for (int j = 0; j < 8; ++j)
                hv[j] = h32[(size_t)e[j] * 64 + lane];
#pragma unroll
            for (int j = 0; j < 8; ++j) {
                a0 += bflo(hv[j]);
                a1 += bfhi(hv[j]);
            }
        }
        for (; i < end; ++i) {
            uint hv = h32[(size_t)adj[i] * 64 + lane];
            a0 += bflo(hv);
            a1 += bfhi(hv);
        }
        a0 = fmaf(a0, dvd, b0);
        a1 = fmaf(a1, dvd, b1);
        agg[(size_t)d * 64 + lane] = bf16rne(a0) | (bf16rne(a1) << 16);
        ps0 += a0; pq0 += a0 * a0;
        ps1 += a1; pq1 += a1 * a1;
    }
    atomicAdd(&ls[c0], ps0);
    atomicAdd(&ls[c0 + 1], ps1);
    atomicAdd(&ls[128 + c0], pq0);
    atomicAdd(&ls[128 + c0 + 1], pq1);
    __syncthreads();
    atomicAdd(&colsum[tid], ls[tid]);
}

// ---------------- pool + linear (BN affine computed in-block) -------------

__global__ __launch_bounds__(256) void k_pool(
    const uint* __restrict__ agg, const int* __restrict__ batch,
    const float* __restrict__ cs, const float* __restrict__ gg,
    const float* __restrict__ be,
    const float* __restrict__ Wl, const float* __restrict__ bl,
    float* __restrict__ out) {
    __shared__ float scsh[256];
    int tid = threadIdx.x;
    if (tid < 128) {
        float s = cs[tid], q = cs[128 + tid];
        float m = s * (1.0f / Nn);
        float var = q * (1.0f / Nn) - m * m;
        float istd = rsqrtf(var + EPSb);
        float sc = istd * gg[tid];
        scsh[tid] = sc;
        scsh[128 + tid] = fmaf(-m, sc, be[tid]);
    }
    __syncthreads();
    int lane = tid & 63;
    int g = (blockIdx.x * blockDim.x + tid) >> 6;
    if (g >= Gg) return;
    int lo = 0, hi = Nn;
    while (lo < hi) { int mid = (lo + hi) >> 1; if (batch[mid] < g) lo = mid + 1; else hi = mid; }
    int beg = lo;
    hi = Nn;
    while (lo < hi) { int mid = (lo + hi) >> 1; if (batch[mid] < g + 1) lo = mid + 1; else hi = mid; }
    int end = lo;
    int c0 = lane * 2;
    float sc0 = scsh[c0], sh0 = scsh[128 + c0];
    float sc1 = scsh[c0 + 1], sh1 = scsh[128 + c0 + 1];
    float s0 = 0.f, s1 = 0.f;
    for (int n = beg; n < end; ++n) {
        uint v = agg[(size_t)n * 64 + lane];
        s0 += fmaxf(fmaf(bflo(v), sc0, sh0), 0.f);
        s1 += fmaxf(fmaf(bfhi(v), sc1, sh1), 0.f);
    }
    float inv = 1.0f / fmaxf((float)(end - beg), 1.0f);
    float part = (s0 * inv) * Wl[c0] + (s1 * inv) * Wl[c0 + 1];
#pragma unroll
    for (int off = 32; off; off >>= 1) part += __shfl_down(part, off);
    if (lane == 0) out[g] = part + bl[0];
}

// ---------------- launch --------------------------------------------------

extern "C" void kernel_launch(void* const* d_in, const int* in_sizes, int n_in,
                              void* d_out, int out_size, void* d_ws, size_t ws_size,
                              hipStream_t stream) {
    const float* x   = (const float*)d_in[0];
    const int*   ei  = (const int*)d_in[1];
    const int*   src = ei;
    const int*   dst = ei + Ee;
    const int*   bat = (const int*)d_in[2];
    const float* W1 = (const float*)d_in[3];
    const float* b1 = (const float*)d_in[4];
    const float* g1 = (const float*)d_in[5];
    const float* be1 = (const float*)d_in[6];
    const float* W2 = (const float*)d_in[7];
    const float* b2 = (const float*)d_in[8];
    const float* g2 = (const float*)d_in[9];
    const float* be2 = (const float*)d_in[10];
    const float* W3 = (const float*)d_in[11];
    const float* b3 = (const float*)d_in[12];
    const float* g3 = (const float*)d_in[13];
    const float* be3 = (const float*)d_in[14];
    const float* Wl = (const float*)d_in[15];
    const float* bl = (const float*)d_in[16];
    float* out = (float*)d_out;

    char* w = (char*)d_ws;
    auto alloc = [&](size_t bytes) {
        void* p = (void*)w;
        w += (bytes + 255) & ~(size_t)255;
        return p;
    };
    // deg, cursor, colsum first and contiguous: one memset zeroes all three
    int*   deg    = (int*)alloc((size_t)Nn * 4);
    int*   cursor = (int*)alloc((size_t)Nn * 4);
    float* colsum = (float*)alloc(768 * 4);   // 3 layers x 256
    size_t zspan  = (size_t)((char*)(colsum + 768) - (char*)deg);
    int*   offs   = (int*)alloc((size_t)(Nn + 1) * 4);
    int*   bsum   = (int*)alloc(256 * 4);
    float* dinv   = (float*)alloc((size_t)Nn * 4);
    uint*  Wt     = (uint*)alloc((size_t)3 * 8192 * 4);
    int*   adj    = (int*)alloc((size_t)(Ee + Nn) * 4);   // src-only, 4B/edge
    uint*  tmp    = (uint*)alloc((size_t)Nn * 64 * 4);    // bf16-packed h'
    uint*  agg    = (uint*)alloc((size_t)Nn * 64 * 4);    // bf16-packed agg

    float* csA = colsum;        // stats of agg1 (uses g1/be1)
    float* csB = colsum + 256;  // stats of agg2 (uses g2/be2)
    float* csC = colsum + 512;  // stats of agg3 (uses g3/be3)

    // graph preprocessing + weight conversion
    hipMemsetAsync(deg, 0, zspan, stream);
    k_deg<<<(Ee + 255) / 256, 256, 0, stream>>>(dst, deg);
    k_scan1<<<NB_SCAN, 256, 0, stream>>>(deg, bsum);
    k_scan3<<<NB_SCAN, 256, 0, stream>>>(deg, bsum, offs, dinv);
    k_fill<<<(Ee + Nn + 255) / 256, 256, 0, stream>>>(src, dst, offs, cursor, adj);
    k_wconv3<<<96, 256, 0, stream>>>(W1, W2, W3, Wt);
    // layer 1
    k_gemm<<<GEMM_BLOCKS, 256, 0, stream>>>(x, (const uint*)0, Wt, dinv,
                                            (const float*)0, (const float*)0,
                                            (const float*)0, tmp, 0);
    k_agg<<<AGG_BLOCKS, 256, 0, stream>>>(tmp, offs, adj, dinv, b1, agg, csA);
    // layer 2
    k_gemm<<<GEMM_BLOCKS, 256, 0, stream>>>((const float*)0, agg, Wt + 8192, dinv,
                                            csA, g1, be1, tmp, 1);
    k_agg<<<AGG_BLOCKS, 256, 0, stream>>>(tmp, offs, adj, dinv, b2, agg, csB);
    // layer 3
    k_gemm<<<GEMM_BLOCKS, 256, 0, stream>>>((const float*)0, agg, Wt + 16384, dinv,
                                            csB, g2, be2, tmp, 1);
    k_agg<<<AGG_BLOCKS, 256, 0, stream>>>(tmp, offs, adj, dinv, b3, agg, csC);
    // pool + linear
    k_pool<<<(Gg * 64 + 255) / 256, 256, 0, stream>>>(agg, bat, csC, g3, be3,
                                                      Wl, bl, out);
}

// Round 12
// 560.422 us; speedup vs baseline: 1.1237x; 1.1237x over previous
//
#include <hip/hip_runtime.h>
#include <hip/hip_bf16.h>

#define Nn 100000
#define Ee 1600000
#define Hh 128
#define Gg 1000
#define EPSb 1e-5f

#define SCAN_CHUNK 1024
#define NB_SCAN 98          // ceil(100000/1024)
#define AGG_BLOCKS 2048
#define NWAVES (AGG_BLOCKS * 4)   // 8192
#define GEMM_BLOCKS 391     // x2 tiles each = 782 = ceil(100000/128)

#define BKT 196             // buckets = ceil(100000/512)
#define BSTRIDE 12288       // staging slots per bucket (mean 8192, +45 sigma)
#define FILL_CHUNK 4096
#define FILL_BLOCKS 391     // ceil(1600000/4096)

typedef unsigned int uint;
typedef short short8 __attribute__((ext_vector_type(8)));
typedef float floatx4 __attribute__((ext_vector_type(4)));

// round-to-nearest-even f32 -> bf16 (as low 16 bits of return)
static __device__ __forceinline__ uint bf16rne(float f) {
    uint u = __float_as_uint(f);
    return (u + 0x7fffu + ((u >> 16) & 1u)) >> 16;
}
static __device__ __forceinline__ float bflo(uint u) { return __uint_as_float(u << 16); }
static __device__ __forceinline__ float bfhi(uint u) { return __uint_as_float(u & 0xffff0000u); }

// ---------------- graph preprocessing ----------------
// deg/bcnt/colsum zeroed by one hipMemsetAsync. deg = in-degree (no self-loop);
// offs = CSR over in-edges only; self-loop handled directly in k_agg;
// dinv = rsqrt(deg+1). dinv factorization: GEMM pre-scales rows by dinv[src],
// k_agg applies dinv[d] once per node. adjacency = src index only (4B/edge).

__global__ void k_deg(const int* __restrict__ dst, int* __restrict__ deg) {
    int i = blockIdx.x * blockDim.x + threadIdx.x;
    if (i < Ee) atomicAdd(&deg[dst[i]], 1);
}

__global__ void k_scan1(const int* __restrict__ deg, int* __restrict__ bsum) {
    __shared__ int ls[256];
    int t = threadIdx.x;
    int base = blockIdx.x * SCAN_CHUNK + t * 4;
    int s = 0;
#pragma unroll
    for (int j = 0; j < 4; ++j) { int i = base + j; if (i < Nn) s += deg[i]; }
    ls[t] = s;
    __syncthreads();
    for (int off = 128; off; off >>= 1) {
        if (t < off) ls[t] += ls[t + off];
        __syncthreads();
    }
    if (t == 0) bsum[blockIdx.x] = ls[0];
}

// scan3: in-block scan of the 98 block sums, per-block exclusive scan over
// deg, emits offs (in-edges) and dinv (with +1 for the self-loop).
__global__ void k_scan3(const int* __restrict__ deg, const int* __restrict__ bsum,
                        int* __restrict__ offs, float* __restrict__ dinv) {
    __shared__ int ls[256];
    __shared__ int bs[128];
    int t = threadIdx.x;
    if (t < 128) bs[t] = (t < NB_SCAN) ? bsum[t] : 0;
    int base = blockIdx.x * SCAN_CHUNK + t * 4;
    int d[4]; int s = 0;
#pragma unroll
    for (int j = 0; j < 4; ++j) {
        int i = base + j;
        d[j] = (i < Nn) ? deg[i] : 0;
        s += d[j];
    }
    ls[t] = s;
    __syncthreads();
    for (int off = 1; off < 128; off <<= 1) {
        int u = (t >= off && t < 128) ? bs[t - off] : 0;
        __syncthreads();
        if (t < 128) bs[t] += u;
        __syncthreads();
    }
    for (int off = 1; off < 256; off <<= 1) {
        int u = (t >= off) ? ls[t - off] : 0;
        __syncthreads();
        ls[t] += u;
        __syncthreads();
    }
    int blockBase = (blockIdx.x == 0) ? 0 : bs[blockIdx.x - 1];
    int run = blockBase + ls[t] - s;   // exclusive prefix for this thread
#pragma unroll
    for (int j = 0; j < 4; ++j) {
        int i = base + j;
        if (i < Nn) {
            offs[i] = run;
            dinv[i] = rsqrtf((float)(d[j] + 1));
        }
        run += d[j];
    }
    if (blockIdx.x == 0 && t == 0) offs[Nn] = Ee;
}

// pass A: privatized counting sort by dst>>9. Packs (src | dlow<<17) in 4B.
// Per-bucket appends are contiguous -> coalesced staging writes.
__global__ __launch_bounds__(256) void k_bucket(
    const int* __restrict__ src, const int* __restrict__ dst,
    int* __restrict__ bcnt, uint* __restrict__ stage) {
    __shared__ int cnt[BKT];
    __shared__ int base[BKT];
    int t = threadIdx.x;
    if (t < BKT) cnt[t] = 0;
    __syncthreads();
    int e0 = blockIdx.x * FILL_CHUNK;
    int slot[16], bkt[16];
#pragma unroll
    for (int j = 0; j < 16; ++j) {
        int i = e0 + j * 256 + t;
        if (i < Ee) {
            int b = dst[i] >> 9;
            bkt[j] = b;
            slot[j] = atomicAdd(&cnt[b], 1);
        } else bkt[j] = -1;
    }
    __syncthreads();
    if (t < BKT) base[t] = atomicAdd(&bcnt[t], cnt[t]);
    __syncthreads();
#pragma unroll
    for (int j = 0; j < 16; ++j) {
        if (bkt[j] >= 0) {
            int i = e0 + j * 256 + t;
            int b = bkt[j];
            int p = base[b] + slot[j];
            if (p < BSTRIDE)
                stage[(size_t)b * BSTRIDE + p] =
                    (uint)src[i] | (((uint)dst[i] & 511u) << 17);
        }
    }
}

// pass B: one block per bucket; LDS cursors; scatter into the bucket's
// ~33KB CSR span (L2-resident -> lines written back once).
__global__ __launch_bounds__(256) void k_scatter(
    const int* __restrict__ bcnt, const uint* __restrict__ stage,
    const int* __restrict__ offs, int* __restrict__ adj) {
    __shared__ int lcur[512];
    int b = blockIdx.x;
    int t = threadIdx.x;
    lcur[t] = 0; lcur[t + 256] = 0;
    __syncthreads();
    int n = bcnt[b];
    if (n > BSTRIDE) n = BSTRIDE;
    int dbase = b << 9;
    const uint* sp = stage + (size_t)b * BSTRIDE;
    for (int i = t; i < n; i += 256) {
        uint e = sp[i];
        int s = (int)(e & 0x1FFFFu);
        int dl = (int)(e >> 17);
        int pos = offs[dbase + dl] + atomicAdd(&lcur[dl], 1);
        adj[pos] = s;
    }
}

// ------- W conversion (all 3 layers): Wt[l][n][k/2] = bf16(W[k][n],W[k+1][n]) --

__global__ void k_wconv3(const float* __restrict__ W1, const float* __restrict__ W2,
                         const float* __restrict__ W3, uint* __restrict__ Wt) {
    int idx = blockIdx.x * blockDim.x + threadIdx.x;   // 3*8192
    if (idx >= 3 * 8192) return;
    const float* W = (idx < 8192) ? W1 : ((idx < 16384) ? W2 : W3);
    int k = idx & 8191;
    int n = k >> 6, ku = k & 63;
    uint lo = bf16rne(W[(size_t)(2 * ku) * 128 + n]);
    uint hi = bf16rne(W[(size_t)(2 * ku + 1) * 128 + n]);
    Wt[(size_t)(idx >> 13) * 8192 + n * 64 + ku] = lo | (hi << 16);
}

// ---------------- MFMA GEMM: tmp(bf16) = dinv[node] * (act(in) @ W) --------
// mode 0: in = fp32 x, identity act. mode 1: in = bf16 agg, act = relu(bn).
// 2 row-tiles per block: W staged once; tile-1 global loads issued before
// tile-0's MFMA (async-stage split). Epilogue scales rows by dinv[node].

__global__ __launch_bounds__(256, 2) void k_gemm(
    const float* __restrict__ inf, const uint* __restrict__ inb,
    const uint* __restrict__ Wtp, const float* __restrict__ dinv,
    const float* __restrict__ cs, const float* __restrict__ gg,
    const float* __restrict__ be,
    uint* __restrict__ outb, int mode) {
    __shared__ uint XT[128][64];
    __shared__ uint WT[128][64];
    __shared__ float scsh[256];   // sc[128], sh[128]
    int t = threadIdx.x;
    int r = t >> 1, half = t & 1;

    if (mode && t < 128) {
        float s = cs[t], q = cs[128 + t];
        float m = s * (1.0f / Nn);
        float var = q * (1.0f / Nn) - m * m;
        float istd = rsqrtf(var + EPSb);
        float sc = istd * gg[t];
        scsh[t] = sc;
        scsh[128 + t] = fmaf(-m, sc, be[t]);
    }
    {   // stage W^T once (already packed bf16)
        const uint* sp = Wtp + (size_t)r * 64 + half * 32;
#pragma unroll
        for (int q = 0; q < 8; ++q) {
            uint4 v = *(const uint4*)(sp + q * 4);
            int g = half * 8 + q;
            *(uint4*)&WT[r][(g ^ (r & 7)) << 2] = v;
        }
    }

    float4 xf[16];   // mode-0 staging regs
    uint4  xb[8];    // mode-1 staging regs

    // ---- issue loads for tile 0 ----
    int rb0 = blockIdx.x * 128;
    {
        int grc = rb0 + r;
        if (grc >= Nn) grc = Nn - 1;
        if (mode == 0) {
            const float* sp = inf + (size_t)grc * 128 + half * 64;
#pragma unroll
            for (int q = 0; q < 8; ++q) {
                xf[2 * q]     = *(const float4*)(sp + q * 8);
                xf[2 * q + 1] = *(const float4*)(sp + q * 8 + 4);
            }
        } else {
            const uint* sp = inb + (size_t)grc * 64 + half * 32;
#pragma unroll
            for (int q = 0; q < 8; ++q) xb[q] = *(const uint4*)(sp + q * 4);
        }
    }
    __syncthreads();   // WT + scsh ready

    // ---- transform + write XT (tile 0) ----
#pragma unroll
    for (int q = 0; q < 8; ++q) {
        uint4 o;
        if (mode == 0) {
            float4 v0 = xf[2 * q], v1 = xf[2 * q + 1];
            o.x = bf16rne(v0.x) | (bf16rne(v0.y) << 16);
            o.y = bf16rne(v0.z) | (bf16rne(v0.w) << 16);
            o.z = bf16rne(v1.x) | (bf16rne(v1.y) << 16);
            o.w = bf16rne(v1.z) | (bf16rne(v1.w) << 16);
        } else {
            uint4 v = xb[q];
            int fb = half * 64 + q * 8;
            float av[8] = {bflo(v.x), bfhi(v.x), bflo(v.y), bfhi(v.y),
                           bflo(v.z), bfhi(v.z), bflo(v.w), bfhi(v.w)};
            uint oo[4];
#pragma unroll
            for (int k2 = 0; k2 < 4; ++k2) {
                float lo = fmaxf(fmaf(av[2 * k2], scsh[fb + 2 * k2],
                                      scsh[128 + fb + 2 * k2]), 0.f);
                float hi = fmaxf(fmaf(av[2 * k2 + 1], scsh[fb + 2 * k2 + 1],
                                      scsh[128 + fb + 2 * k2 + 1]), 0.f);
                oo[k2] = bf16rne(lo) | (bf16rne(hi) << 16);
            }
            o = make_uint4(oo[0], oo[1], oo[2], oo[3]);
        }
        int g = half * 8 + q;
        *(uint4*)&XT[r][(g ^ (r & 7)) << 2] = o;
    }
    __syncthreads();   // XT(tile0) ready

    int l = t & 63, w = t >> 6;
    int nb = (w >> 1) * 64;
    int fb2 = (w & 1) * 64;
    int lr = l & 15, lk = l >> 4;
    floatx4 zero = {0.f, 0.f, 0.f, 0.f};

    // ---- issue loads for tile 1 (hidden under tile-0 MFMA) ----
    int rb1 = (blockIdx.x + GEMM_BLOCKS) * 128;
    {
        int grc = rb1 + r;
        if (grc >= Nn) grc = Nn - 1;
        if (mode == 0) {
            const float* sp = inf + (size_t)grc * 128 + half * 64;
#pragma unroll
            for (int q = 0; q < 8; ++q) {
                xf[2 * q]     = *(const float4*)(sp + q * 8);
                xf[2 * q + 1] = *(const float4*)(sp + q * 8 + 4);
            }
        } else {
            const uint* sp = inb + (size_t)grc * 64 + half * 32;
#pragma unroll
            for (int q = 0; q < 8; ++q) xb[q] = *(const uint4*)(sp + q * 4);
        }
    }

    // ---- MFMA + store, tile 0 ----
    {
        floatx4 acc[4][4];
#pragma unroll
        for (int mi = 0; mi < 4; ++mi)
#pragma unroll
            for (int ni = 0; ni < 4; ++ni) acc[mi][ni] = zero;
#pragma unroll
        for (int kc = 0; kc < 4; ++kc) {
            short8 xfr[4], wfr[4];
            int g = kc * 4 + lk;
#pragma unroll
            for (int mi = 0; mi < 4; ++mi) {
                int rr = nb + mi * 16 + lr;
                xfr[mi] = *(const short8*)&XT[rr][(g ^ (rr & 7)) << 2];
            }
#pragma unroll
            for (int ni = 0; ni < 4; ++ni) {
                int rr = fb2 + ni * 16 + lr;
                wfr[ni] = *(const short8*)&WT[rr][(g ^ (rr & 7)) << 2];
            }
#pragma unroll
            for (int mi = 0; mi < 4; ++mi)
#pragma unroll
                for (int ni = 0; ni < 4; ++ni)
                    acc[mi][ni] = __builtin_amdgcn_mfma_f32_16x16x32_bf16(
                        wfr[ni], xfr[mi], acc[mi][ni], 0, 0, 0);
        }
#pragma unroll
        for (int mi = 0; mi < 4; ++mi) {
            int node = rb0 + nb + mi * 16 + lr;
            if (node < Nn) {
                float dv = dinv[node];
                uint* op = outb + (size_t)node * 64;
#pragma unroll
                for (int ni = 0; ni < 4; ++ni) {
                    int fo = fb2 + ni * 16 + lk * 4;
                    uint2 o;
                    o.x = bf16rne(acc[mi][ni][0] * dv) | (bf16rne(acc[mi][ni][1] * dv) << 16);
                    o.y = bf16rne(acc[mi][ni][2] * dv) | (bf16rne(acc[mi][ni][3] * dv) << 16);
                    *(uint2*)(op + (fo >> 1)) = o;
                }
            }
        }
    }
    __syncthreads();   // all XT(tile0) reads done

    // ---- transform + write XT (tile 1) ----
#pragma unroll
    for (int q = 0; q < 8; ++q) {
        uint4 o;
        if (mode == 0) {
            float4 v0 = xf[2 * q], v1 = xf[2 * q + 1];
            o.x = bf16rne(v0.x) | (bf16rne(v0.y) << 16);
            o.y = bf16rne(v0.z) | (bf16rne(v0.w) << 16);
            o.z = bf16rne(v1.x) | (bf16rne(v1.y) << 16);
            o.w = bf16rne(v1.z) | (bf16rne(v1.w) << 16);
        } else {
            uint4 v = xb[q];
            int fb = half * 64 + q * 8;
            float av[8] = {bflo(v.x), bfhi(v.x), bflo(v.y), bfhi(v.y),
                           bflo(v.z), bfhi(v.z), bflo(v.w), bfhi(v.w)};
            uint oo[4];
#pragma unroll
            for (int k2 = 0; k2 < 4; ++k2) {
                float lo = fmaxf(fmaf(av[2 * k2], scsh[fb + 2 * k2],
                                      scsh[128 + fb + 2 * k2]), 0.f);
                float hi = fmaxf(fmaf(av[2 * k2 + 1], scsh[fb + 2 * k2 + 1],
                                      scsh[128 + fb + 2 * k2 + 1]), 0.f);
                oo[k2] = bf16rne(lo) | (bf16rne(hi) << 16);
            }
            o = make_uint4(oo[0], oo[1], oo[2], oo[3]);
        }
        int g = half * 8 + q;
        *(uint4*)&XT[r][(g ^ (r & 7)) << 2] = o;
    }
    __syncthreads();   // XT(tile1) ready

    // ---- MFMA + store, tile 1 ----
    {
        floatx4 acc[4][4];
#pragma unroll
        for (int mi = 0; mi < 4; ++mi)
#pragma unroll
            for (int ni = 0; ni < 4; ++ni) acc[mi][ni] = zero;
#pragma unroll
        for (int kc = 0; kc < 4; ++kc) {
            short8 xfr[4], wfr[4];
            int g = kc * 4 + lk;
#pragma unroll
            for (int mi = 0; mi < 4; ++mi) {
                int rr = nb + mi * 16 + lr;
                xfr[mi] = *(const short8*)&XT[rr][(g ^ (rr & 7)) << 2];
            }
#pragma unroll
            for (int ni = 0; ni < 4; ++ni) {
                int rr = fb2 + ni * 16 + lr;
                wfr[ni] = *(const short8*)&WT[rr][(g ^ (rr & 7)) << 2];
            }
#pragma unroll
            for (int mi = 0; mi < 4; ++mi)
#pragma unroll
                for (int ni = 0; ni < 4; ++ni)
                    acc[mi][ni] = __builtin_amdgcn_mfma_f32_16x16x32_bf16(
                        wfr[ni], xfr[mi], acc[mi][ni], 0, 0, 0);
        }
#pragma unroll
        for (int mi = 0; mi < 4; ++mi) {
            int node = rb1 + nb + mi * 16 + lr;
            if (node < Nn) {
                float dv = dinv[node];
                uint* op = outb + (size_t)node * 64;
#pragma unroll
                for (int ni = 0; ni < 4; ++ni) {
                    int fo = fb2 + ni * 16 + lk * 4;
                    uint2 o;
                    o.x = bf16rne(acc[mi][ni][0] * dv) | (bf16rne(acc[mi][ni][1] * dv) << 16);
                    o.y = bf16rne(acc[mi][ni][2] * dv) | (bf16rne(acc[mi][ni][3] * dv) << 16);
                    *(uint2*)(op + (fo >> 1)) = o;
                }
            }
        }
    }
}

// ------- aggregation: agg[d] = dinv[d]*(sum_in h'[src] + h'[d]) + bias -------
// Proven loop shape; src-only adjacency (in-edges), self-loop added directly.

__global__ __launch_bounds__(256) void k_agg(
    const uint* __restrict__ h32, const int* __restrict__ offs,
    const int* __restrict__ adj, const float* __restrict__ dinv,
    const float* __restrict__ bias, uint* __restrict__ agg,
    float* __restrict__ colsum) {
    __shared__ float ls[256];
    int tid = threadIdx.x;
    ls[tid] = 0.f;
    __syncthreads();
    int lane = tid & 63;
    int gw = blockIdx.x * 4 + (tid >> 6);
    int nw = NWAVES;
    int c0 = lane * 2;
    float b0 = bias[c0], b1 = bias[c0 + 1];
    float ps0 = 0.f, pq0 = 0.f, ps1 = 0.f, pq1 = 0.f;
    for (int d = gw; d < Nn; d += nw) {
        int beg = offs[d], end = offs[d + 1];
        float dvd = dinv[d];
        uint hself = h32[(size_t)d * 64 + lane];
        float a0 = bflo(hself), a1 = bfhi(hself);
        int i = beg;
        for (; i + 8 <= end; i += 8) {
            int e[8];
#pragma unroll
            for (int j = 0; j < 8; ++j) e[j] = adj[i + j];
            uint hv[8];
#pragma unroll
            for (int j = 0; j < 8; ++j)
                hv[j] = h32[(size_t)e[j] * 64 + lane];
#pragma unroll
            for (int j = 0; j < 8; ++j) {
                a0 += bflo(hv[j]);
                a1 += bfhi(hv[j]);
            }
        }
        for (; i < end; ++i) {
            uint hv = h32[(size_t)adj[i] * 64 + lane];
            a0 += bflo(hv);
            a1 += bfhi(hv);
        }
        a0 = fmaf(a0, dvd, b0);
        a1 = fmaf(a1, dvd, b1);
        agg[(size_t)d * 64 + lane] = bf16rne(a0) | (bf16rne(a1) << 16);
        ps0 += a0; pq0 += a0 * a0;
        ps1 += a1; pq1 += a1 * a1;
    }
    atomicAdd(&ls[c0], ps0);
    atomicAdd(&ls[c0 + 1], ps1);
    atomicAdd(&ls[128 + c0], pq0);
    atomicAdd(&ls[128 + c0 + 1], pq1);
    __syncthreads();
    atomicAdd(&colsum[tid], ls[tid]);
}

// ---------------- pool + linear (BN affine computed in-block) -------------

__global__ __launch_bounds__(256) void k_pool(
    const uint* __restrict__ agg, const int* __restrict__ batch,
    const float* __restrict__ cs, const float* __restrict__ gg,
    const float* __restrict__ be,
    const float* __restrict__ Wl, const float* __restrict__ bl,
    float* __restrict__ out) {
    __shared__ float scsh[256];
    int tid = threadIdx.x;
    if (tid < 128) {
        float s = cs[tid], q = cs[128 + tid];
        float m = s * (1.0f / Nn);
        float var = q * (1.0f / Nn) - m * m;
        float istd = rsqrtf(var + EPSb);
        float sc = istd * gg[tid];
        scsh[tid] = sc;
        scsh[128 + tid] = fmaf(-m, sc, be[tid]);
    }
    __syncthreads();
    int lane = tid & 63;
    int g = (blockIdx.x * blockDim.x + tid) >> 6;
    if (g >= Gg) return;
    int lo = 0, hi = Nn;
    while (lo < hi) { int mid = (lo + hi) >> 1; if (batch[mid] < g) lo = mid + 1; else hi = mid; }
    int beg = lo;
    hi = Nn;
    while (lo < hi) { int mid = (lo + hi) >> 1; if (batch[mid] < g + 1) lo = mid + 1; else hi = mid; }
    int end = lo;
    int c0 = lane * 2;
    float sc0 = scsh[c0], sh0 = scsh[128 + c0];
    float sc1 = scsh[c0 + 1], sh1 = scsh[128 + c0 + 1];
    float s0 = 0.f, s1 = 0.f;
    for (int n = beg; n < end; ++n) {
        uint v = agg[(size_t)n * 64 + lane];
        s0 += fmaxf(fmaf(bflo(v), sc0, sh0), 0.f);
        s1 += fmaxf(fmaf(bfhi(v), sc1, sh1), 0.f);
    }
    float inv = 1.0f / fmaxf((float)(end - beg), 1.0f);
    float part = (s0 * inv) * Wl[c0] + (s1 * inv) * Wl[c0 + 1];
#pragma unroll
    for (int off = 32; off; off >>= 1) part += __shfl_down(part, off);
    if (lane == 0) out[g] = part + bl[0];
}

// ---------------- launch --------------------------------------------------

extern "C" void kernel_launch(void* const* d_in, const int* in_sizes, int n_in,
                              void* d_out, int out_size, void* d_ws, size_t ws_size,
                              hipStream_t stream) {
    const float* x   = (const float*)d_in[0];
    const int*   ei  = (const int*)d_in[1];
    const int*   src = ei;
    const int*   dst = ei + Ee;
    const int*   bat = (const int*)d_in[2];
    const float* W1 = (const float*)d_in[3];
    const float* b1 = (const float*)d_in[4];
    const float* g1 = (const float*)d_in[5];
    const float* be1 = (const float*)d_in[6];
    const float* W2 = (const float*)d_in[7];
    const float* b2 = (const float*)d_in[8];
    const float* g2 = (const float*)d_in[9];
    const float* be2 = (const float*)d_in[10];
    const float* W3 = (const float*)d_in[11];
    const float* b3 = (const float*)d_in[12];
    const float* g3 = (const float*)d_in[13];
    const float* be3 = (const float*)d_in[14];
    const float* Wl = (const float*)d_in[15];
    const float* bl = (const float*)d_in[16];
    float* out = (float*)d_out;

    char* w = (char*)d_ws;
    auto alloc = [&](size_t bytes) {
        void* p = (void*)w;
        w += (bytes + 255) & ~(size_t)255;
        return p;
    };
    // deg, bcnt, colsum first and contiguous: one memset zeroes all three
    int*   deg    = (int*)alloc((size_t)Nn * 4);
    int*   bcnt   = (int*)alloc(BKT * 4);
    float* colsum = (float*)alloc(768 * 4);   // 3 layers x 256
    size_t zspan  = (size_t)((char*)(colsum + 768) - (char*)deg);
    int*   offs   = (int*)alloc((size_t)(Nn + 1) * 4);
    int*   bsum   = (int*)alloc(256 * 4);
    float* dinv   = (float*)alloc((size_t)Nn * 4);
    uint*  Wt     = (uint*)alloc((size_t)3 * 8192 * 4);
    uint*  stage  = (uint*)alloc((size_t)BKT * BSTRIDE * 4);   // 9.6 MB
    int*   adj    = (int*)alloc((size_t)Ee * 4);               // src-only, in-edges
    uint*  tmp    = (uint*)alloc((size_t)Nn * 64 * 4);    // bf16-packed h'
    uint*  agg    = (uint*)alloc((size_t)Nn * 64 * 4);    // bf16-packed agg

    float* csA = colsum;        // stats of agg1 (uses g1/be1)
    float* csB = colsum + 256;  // stats of agg2 (uses g2/be2)
    float* csC = colsum + 512;  // stats of agg3 (uses g3/be3)

    // graph preprocessing + weight conversion
    hipMemsetAsync(deg, 0, zspan, stream);
    k_deg<<<(Ee + 255) / 256, 256, 0, stream>>>(dst, deg);
    k_scan1<<<NB_SCAN, 256, 0, stream>>>(deg, bsum);
    k_scan3<<<NB_SCAN, 256, 0, stream>>>(deg, bsum, offs, dinv);
    k_bucket<<<FILL_BLOCKS, 256, 0, stream>>>(src, dst, bcnt, stage);
    k_scatter<<<BKT, 256, 0, stream>>>(bcnt, stage, offs, adj);
    k_wconv3<<<96, 256, 0, stream>>>(W1, W2, W3, Wt);
    // layer 1
    k_gemm<<<GEMM_BLOCKS, 256, 0, stream>>>(x, (const uint*)0, Wt, dinv,
                                            (const float*)0, (const float*)0,
                                            (const float*)0, tmp, 0);
    k_agg<<<AGG_BLOCKS, 256, 0, stream>>>(tmp, offs, adj, dinv, b1, agg, csA);
    // layer 2
    k_gemm<<<GEMM_BLOCKS, 256, 0, stream>>>((const float*)0, agg, Wt + 8192, dinv,
                                            csA, g1, be1, tmp, 1);
    k_agg<<<AGG_BLOCKS, 256, 0, stream>>>(tmp, offs, adj, dinv, b2, agg, csB);
    // layer 3
    k_gemm<<<GEMM_BLOCKS, 256, 0, stream>>>((const float*)0, agg, Wt + 16384, dinv,
                                            csB, g2, be2, tmp, 1);
    k_agg<<<AGG_BLOCKS, 256, 0, stream>>>(tmp, offs, adj, dinv, b3, agg, csC);
    // pool + linear
    k_pool<<<(Gg * 64 + 255) / 256, 256, 0, stream>>>(agg, bat, csC, g3, be3,
                                                      Wl, bl, out);
}

// Round 13
// 545.939 us; speedup vs baseline: 1.1535x; 1.0265x over previous
//
#include <hip/hip_runtime.h>
#include <hip/hip_bf16.h>

#define Nn 100000
#define Ee 1600000
#define Hh 128
#define Gg 1000
#define EPSb 1e-5f

#define AGG_BLOCKS 2048
#define NWAVES (AGG_BLOCKS * 4)   // 8192
#define GEMM_BLOCKS 391     // x2 tiles each = 782 = ceil(100000/128)

#define BKT 196             // buckets = ceil(100000/512)
#define BSTRIDE 12288       // staging slots per bucket (mean 8163, +45 sigma)
#define FILL_CHUNK 4096
#define FILL_BLOCKS 391     // ceil(1600000/4096)

typedef unsigned int uint;
typedef short short8 __attribute__((ext_vector_type(8)));
typedef float floatx4 __attribute__((ext_vector_type(4)));

// round-to-nearest-even f32 -> bf16 (as low 16 bits of return)
static __device__ __forceinline__ uint bf16rne(float f) {
    uint u = __float_as_uint(f);
    return (u + 0x7fffu + ((u >> 16) & 1u)) >> 16;
}
static __device__ __forceinline__ float bflo(uint u) { return __uint_as_float(u << 16); }
static __device__ __forceinline__ float bfhi(uint u) { return __uint_as_float(u & 0xffff0000u); }

// ---------------- graph preprocessing ----------------
// deg/bcnt/colsum zeroed by one hipMemsetAsync. deg = in-degree (no self-loop),
// counted INSIDE k_bucket (fold of old k_deg). offs = CSR over in-edges only;
// self-loop handled directly in k_agg; dinv = rsqrt(deg+1).
// dinv factorization: GEMM pre-scales rows by dinv[src]; k_agg applies
// dinv[d] once per node. adjacency = src index only (4B/edge).

// pass A: privatized counting sort by dst>>9 + per-node degree atomics.
// Packs (src | dlow<<17) in 4B. Per-bucket appends contiguous -> coalesced.
__global__ __launch_bounds__(256) void k_bucket(
    const int* __restrict__ src, const int* __restrict__ dst,
    int* __restrict__ deg, int* __restrict__ bcnt, uint* __restrict__ stage) {
    __shared__ int cnt[BKT];
    __shared__ int base[BKT];
    int t = threadIdx.x;
    if (t < BKT) cnt[t] = 0;
    __syncthreads();
    int e0 = blockIdx.x * FILL_CHUNK;
    int slot[16], bkt[16];
#pragma unroll
    for (int j = 0; j < 16; ++j) {
        int i = e0 + j * 256 + t;
        if (i < Ee) {
            int dd = dst[i];
            atomicAdd(&deg[dd], 1);           // folded k_deg
            int b = dd >> 9;
            bkt[j] = b;
            slot[j] = atomicAdd(&cnt[b], 1);
        } else bkt[j] = -1;
    }
    __syncthreads();
    if (t < BKT) base[t] = atomicAdd(&bcnt[t], cnt[t]);
    __syncthreads();
#pragma unroll
    for (int j = 0; j < 16; ++j) {
        if (bkt[j] >= 0) {
            int i = e0 + j * 256 + t;
            int b = bkt[j];
            int p = base[b] + slot[j];
            if (p < BSTRIDE)
                stage[(size_t)b * BSTRIDE + p] =
                    (uint)src[i] | (((uint)dst[i] & 511u) << 17);
        }
    }
}

// scan3b: one block per bucket (512 nodes). Bucket base = scan of bcnt
// (per-bucket edge totals from k_bucket); local exclusive scan over deg.
// Emits offs and dinv. Replaces the old scan1+scan3 pair.
__global__ __launch_bounds__(256) void k_scan3b(
    const int* __restrict__ deg, const int* __restrict__ bcnt,
    int* __restrict__ offs, float* __restrict__ dinv) {
    __shared__ int ls[256];
    __shared__ int bs[256];
    int t = threadIdx.x;
    int b = blockIdx.x;                 // bucket 0..195
    bs[t] = (t < BKT) ? bcnt[t] : 0;
    int base = (b << 9) + t * 2;        // 2 nodes per thread
    int d0 = (base     < Nn) ? deg[base]     : 0;
    int d1 = (base + 1 < Nn) ? deg[base + 1] : 0;
    int s = d0 + d1;
    ls[t] = s;
    __syncthreads();
    for (int off = 1; off < 256; off <<= 1) {
        int u0 = (t >= off) ? bs[t - off] : 0;
        int u1 = (t >= off) ? ls[t - off] : 0;
        __syncthreads();
        bs[t] += u0;
        ls[t] += u1;
        __syncthreads();
    }
    int bucketBase = (b == 0) ? 0 : bs[b - 1];
    int run = bucketBase + ls[t] - s;   // exclusive prefix
    if (base < Nn) {
        offs[base] = run;
        dinv[base] = rsqrtf((float)(d0 + 1));
    }
    run += d0;
    if (base + 1 < Nn) {
        offs[base + 1] = run;
        dinv[base + 1] = rsqrtf((float)(d1 + 1));
    }
    if (b == 0 && t == 0) offs[Nn] = Ee;
}

// pass B: one block per bucket; LDS cursors; scatter into the bucket's
// ~33KB CSR span (L2-resident -> lines written back once).
__global__ __launch_bounds__(256) void k_scatter(
    const int* __restrict__ bcnt, const uint* __restrict__ stage,
    const int* __restrict__ offs, int* __restrict__ adj) {
    __shared__ int lcur[512];
    int b = blockIdx.x;
    int t = threadIdx.x;
    lcur[t] = 0; lcur[t + 256] = 0;
    __syncthreads();
    int n = bcnt[b];
    if (n > BSTRIDE) n = BSTRIDE;
    int dbase = b << 9;
    const uint* sp = stage + (size_t)b * BSTRIDE;
    for (int i = t; i < n; i += 256) {
        uint e = sp[i];
        int s = (int)(e & 0x1FFFFu);
        int dl = (int)(e >> 17);
        int pos = offs[dbase + dl] + atomicAdd(&lcur[dl], 1);
        adj[pos] = s;
    }
}

// ------- W conversion (all 3 layers): Wt[l][n][k/2] = bf16(W[k][n],W[k+1][n]) --

__global__ void k_wconv3(const float* __restrict__ W1, const float* __restrict__ W2,
                         const float* __restrict__ W3, uint* __restrict__ Wt) {
    int idx = blockIdx.x * blockDim.x + threadIdx.x;   // 3*8192
    if (idx >= 3 * 8192) return;
    const float* W = (idx < 8192) ? W1 : ((idx < 16384) ? W2 : W3);
    int k = idx & 8191;
    int n = k >> 6, ku = k & 63;
    uint lo = bf16rne(W[(size_t)(2 * ku) * 128 + n]);
    uint hi = bf16rne(W[(size_t)(2 * ku + 1) * 128 + n]);
    Wt[(size_t)(idx >> 13) * 8192 + n * 64 + ku] = lo | (hi << 16);
}

// ---------------- MFMA GEMM: tmp(bf16) = dinv[node] * (act(in) @ W) --------
// mode 0: in = fp32 x, identity act. mode 1: in = bf16 agg, act = relu(bn).
// 2 row-tiles per block: W staged once; tile-1 global loads issued before
// tile-0's MFMA (async-stage split). Epilogue scales rows by dinv[node].

__global__ __launch_bounds__(256, 2) void k_gemm(
    const float* __restrict__ inf, const uint* __restrict__ inb,
    const uint* __restrict__ Wtp, const float* __restrict__ dinv,
    const float* __restrict__ cs, const float* __restrict__ gg,
    const float* __restrict__ be,
    uint* __restrict__ outb, int mode) {
    __shared__ uint XT[128][64];
    __shared__ uint WT[128][64];
    __shared__ float scsh[256];   // sc[128], sh[128]
    int t = threadIdx.x;
    int r = t >> 1, half = t & 1;

    if (mode && t < 128) {
        float s = cs[t], q = cs[128 + t];
        float m = s * (1.0f / Nn);
        float var = q * (1.0f / Nn) - m * m;
        float istd = rsqrtf(var + EPSb);
        float sc = istd * gg[t];
        scsh[t] = sc;
        scsh[128 + t] = fmaf(-m, sc, be[t]);
    }
    {   // stage W^T once (already packed bf16)
        const uint* sp = Wtp + (size_t)r * 64 + half * 32;
#pragma unroll
        for (int q = 0; q < 8; ++q) {
            uint4 v = *(const uint4*)(sp + q * 4);
            int g = half * 8 + q;
            *(uint4*)&WT[r][(g ^ (r & 7)) << 2] = v;
        }
    }

    float4 xf[16];   // mode-0 staging regs
    uint4  xb[8];    // mode-1 staging regs

    // ---- issue loads for tile 0 ----
    int rb0 = blockIdx.x * 128;
    {
        int grc = rb0 + r;
        if (grc >= Nn) grc = Nn - 1;
        if (mode == 0) {
            const float* sp = inf + (size_t)grc * 128 + half * 64;
#pragma unroll
            for (int q = 0; q < 8; ++q) {
                xf[2 * q]     = *(const float4*)(sp + q * 8);
                xf[2 * q + 1] = *(const float4*)(sp + q * 8 + 4);
            }
        } else {
            const uint* sp = inb + (size_t)grc * 64 + half * 32;
#pragma unroll
            for (int q = 0; q < 8; ++q) xb[q] = *(const uint4*)(sp + q * 4);
        }
    }
    __syncthreads();   // WT + scsh ready

    // ---- transform + write XT (tile 0) ----
#pragma unroll
    for (int q = 0; q < 8; ++q) {
        uint4 o;
        if (mode == 0) {
            float4 v0 = xf[2 * q], v1 = xf[2 * q + 1];
            o.x = bf16rne(v0.x) | (bf16rne(v0.y) << 16);
            o.y = bf16rne(v0.z) | (bf16rne(v0.w) << 16);
            o.z = bf16rne(v1.x) | (bf16rne(v1.y) << 16);
            o.w = bf16rne(v1.z) | (bf16rne(v1.w) << 16);
        } else {
            uint4 v = xb[q];
            int fb = half * 64 + q * 8;
            float av[8] = {bflo(v.x), bfhi(v.x), bflo(v.y), bfhi(v.y),
                           bflo(v.z), bfhi(v.z), bflo(v.w), bfhi(v.w)};
            uint oo[4];
#pragma unroll
            for (int k2 = 0; k2 < 4; ++k2) {
                float lo = fmaxf(fmaf(av[2 * k2], scsh[fb + 2 * k2],
                                      scsh[128 + fb + 2 * k2]), 0.f);
                float hi = fmaxf(fmaf(av[2 * k2 + 1], scsh[fb + 2 * k2 + 1],
                                      scsh[128 + fb + 2 * k2 + 1]), 0.f);
                oo[k2] = bf16rne(lo) | (bf16rne(hi) << 16);
            }
            o = make_uint4(oo[0], oo[1], oo[2], oo[3]);
        }
        int g = half * 8 + q;
        *(uint4*)&XT[r][(g ^ (r & 7)) << 2] = o;
    }
    __syncthreads();   // XT(tile0) ready

    int l = t & 63, w = t >> 6;
    int nb = (w >> 1) * 64;
    int fb2 = (w & 1) * 64;
    int lr = l & 15, lk = l >> 4;
    floatx4 zero = {0.f, 0.f, 0.f, 0.f};

    // ---- issue loads for tile 1 (hidden under tile-0 MFMA) ----
    int rb1 = (blockIdx.x + GEMM_BLOCKS) * 128;
    {
        int grc = rb1 + r;
        if (grc >= Nn) grc = Nn - 1;
        if (mode == 0) {
            const float* sp = inf + (size_t)grc * 128 + half * 64;
#pragma unroll
            for (int q = 0; q < 8; ++q) {
                xf[2 * q]     = *(const float4*)(sp + q * 8);
                xf[2 * q + 1] = *(const float4*)(sp + q * 8 + 4);
            }
        } else {
            const uint* sp = inb + (size_t)grc * 64 + half * 32;
#pragma unroll
            for (int q = 0; q < 8; ++q) xb[q] = *(const uint4*)(sp + q * 4);
        }
    }

    // ---- MFMA + store, tile 0 ----
    {
        floatx4 acc[4][4];
#pragma unroll
        for (int mi = 0; mi < 4; ++mi)
#pragma unroll
            for (int ni = 0; ni < 4; ++ni) acc[mi][ni] = zero;
#pragma unroll
        for (int kc = 0; kc < 4; ++kc) {
            short8 xfr[4], wfr[4];
            int g = kc * 4 + lk;
#pragma unroll
            for (int mi = 0; mi < 4; ++mi) {
                int rr = nb + mi * 16 + lr;
                xfr[mi] = *(const short8*)&XT[rr][(g ^ (rr & 7)) << 2];
            }
#pragma unroll
            for (int ni = 0; ni < 4; ++ni) {
                int rr = fb2 + ni * 16 + lr;
                wfr[ni] = *(const short8*)&WT[rr][(g ^ (rr & 7)) << 2];
            }
#pragma unroll
            for (int mi = 0; mi < 4; ++mi)
#pragma unroll
                for (int ni = 0; ni < 4; ++ni)
                    acc[mi][ni] = __builtin_amdgcn_mfma_f32_16x16x32_bf16(
                        wfr[ni], xfr[mi], acc[mi][ni], 0, 0, 0);
        }
#pragma unroll
        for (int mi = 0; mi < 4; ++mi) {
            int node = rb0 + nb + mi * 16 + lr;
            if (node < Nn) {
                float dv = dinv[node];
                uint* op = outb + (size_t)node * 64;
#pragma unroll
                for (int ni = 0; ni < 4; ++ni) {
                    int fo = fb2 + ni * 16 + lk * 4;
                    uint2 o;
                    o.x = bf16rne(acc[mi][ni][0] * dv) | (bf16rne(acc[mi][ni][1] * dv) << 16);
                    o.y = bf16rne(acc[mi][ni][2] * dv) | (bf16rne(acc[mi][ni][3] * dv) << 16);
                    *(uint2*)(op + (fo >> 1)) = o;
                }
            }
        }
    }
    __syncthreads();   // all XT(tile0) reads done

    // ---- transform + write XT (tile 1) ----
#pragma unroll
    for (int q = 0; q < 8; ++q) {
        uint4 o;
        if (mode == 0) {
            float4 v0 = xf[2 * q], v1 = xf[2 * q + 1];
            o.x = bf16rne(v0.x) | (bf16rne(v0.y) << 16);
            o.y = bf16rne(v0.z) | (bf16rne(v0.w) << 16);
            o.z = bf16rne(v1.x) | (bf16rne(v1.y) << 16);
            o.w = bf16rne(v1.z) | (bf16rne(v1.w) << 16);
        } else {
            uint4 v = xb[q];
            int fb = half * 64 + q * 8;
            float av[8] = {bflo(v.x), bfhi(v.x), bflo(v.y), bfhi(v.y),
                           bflo(v.z), bfhi(v.z), bflo(v.w), bfhi(v.w)};
            uint oo[4];
#pragma unroll
            for (int k2 = 0; k2 < 4; ++k2) {
                float lo = fmaxf(fmaf(av[2 * k2], scsh[fb + 2 * k2],
                                      scsh[128 + fb + 2 * k2]), 0.f);
                float hi = fmaxf(fmaf(av[2 * k2 + 1], scsh[fb + 2 * k2 + 1],
                                      scsh[128 + fb + 2 * k2 + 1]), 0.f);
                oo[k2] = bf16rne(lo) | (bf16rne(hi) << 16);
            }
            o = make_uint4(oo[0], oo[1], oo[2], oo[3]);
        }
        int g = half * 8 + q;
        *(uint4*)&XT[r][(g ^ (r & 7)) << 2] = o;
    }
    __syncthreads();   // XT(tile1) ready

    // ---- MFMA + store, tile 1 ----
    {
        floatx4 acc[4][4];
#pragma unroll
        for (int mi = 0; mi < 4; ++mi)
#pragma unroll
            for (int ni = 0; ni < 4; ++ni) acc[mi][ni] = zero;
#pragma unroll
        for (int kc = 0; kc < 4; ++kc) {
            short8 xfr[4], wfr[4];
            int g = kc * 4 + lk;
#pragma unroll
            for (int mi = 0; mi < 4; ++mi) {
                int rr = nb + mi * 16 + lr;
                xfr[mi] = *(const short8*)&XT[rr][(g ^ (rr & 7)) << 2];
            }
#pragma unroll
            for (int ni = 0; ni < 4; ++ni) {
                int rr = fb2 + ni * 16 + lr;
                wfr[ni] = *(const short8*)&WT[rr][(g ^ (rr & 7)) << 2];
            }
#pragma unroll
            for (int mi = 0; mi < 4; ++mi)
#pragma unroll
                for (int ni = 0; ni < 4; ++ni)
                    acc[mi][ni] = __builtin_amdgcn_mfma_f32_16x16x32_bf16(
                        wfr[ni], xfr[mi], acc[mi][ni], 0, 0, 0);
        }
#pragma unroll
        for (int mi = 0; mi < 4; ++mi) {
            int node = rb1 + nb + mi * 16 + lr;
            if (node < Nn) {
                float dv = dinv[node];
                uint* op = outb + (size_t)node * 64;
#pragma unroll
                for (int ni = 0; ni < 4; ++ni) {
                    int fo = fb2 + ni * 16 + lk * 4;
                    uint2 o;
                    o.x = bf16rne(acc[mi][ni][0] * dv) | (bf16rne(acc[mi][ni][1] * dv) << 16);
                    o.y = bf16rne(acc[mi][ni][2] * dv) | (bf16rne(acc[mi][ni][3] * dv) << 16);
                    *(uint2*)(op + (fo >> 1)) = o;
                }
            }
        }
    }
}

// ------- aggregation: agg[d] = dinv[d]*(sum_in h'[src] + h'[d]) + bias -------
// Proven loop shape (measured floor); src-only adjacency, self-loop direct.

__global__ __launch_bounds__(256) void k_agg(
    const uint* __restrict__ h32, const int* __restrict__ offs,
    const int* __restrict__ adj, const float* __restrict__ dinv,
    const float* __restrict__ bias, uint* __restrict__ agg,
    float* __restrict__ colsum) {
    __shared__ float ls[256];
    int tid = threadIdx.x;
    ls[tid] = 0.f;
    __syncthreads();
    int lane = tid & 63;
    int gw = blockIdx.x * 4 + (tid >> 6);
    int nw = NWAVES;
    int c0 = lane * 2;
    float b0 = bias[c0], b1 = bias[c0 + 1];
    float ps0 = 0.f, pq0 = 0.f, ps1 = 0.f, pq1 = 0.f;
    for (int d = gw; d < Nn; d += nw) {
        int beg = offs[d], end = offs[d + 1];
        float dvd = dinv[d];
        uint hself = h32[(size_t)d * 64 + lane];
        float a0 = bflo(hself), a1 = bfhi(hself);
        int i = beg;
        for (; i + 8 <= end; i += 8) {
            int e[8];
#pragma unroll
            for (int j = 0; j < 8; ++j) e[j] = adj[i + j];
            uint hv[8];
#pragma unroll
            for (int j = 0; j < 8; ++j)
                hv[j] = h32[(size_t)e[j] * 64 + lane];
#pragma unroll
            for (int j = 0; j < 8; ++j) {
                a0 += bflo(hv[j]);
                a1 += bfhi(hv[j]);
            }
        }
        for (; i < end; ++i) {
            uint hv = h32[(size_t)adj[i] * 64 + lane];
            a0 += bflo(hv);
            a1 += bfhi(hv);
        }
        a0 = fmaf(a0, dvd, b0);
        a1 = fmaf(a1, dvd, b1);
        agg[(size_t)d * 64 + lane] = bf16rne(a0) | (bf16rne(a1) << 16);
        ps0 += a0; pq0 += a0 * a0;
        ps1 += a1; pq1 += a1 * a1;
    }
    atomicAdd(&ls[c0], ps0);
    atomicAdd(&ls[c0 + 1], ps1);
    atomicAdd(&ls[128 + c0], pq0);
    atomicAdd(&ls[128 + c0 + 1], pq1);
    __syncthreads();
    atomicAdd(&colsum[tid], ls[tid]);
}

// ---------------- pool + linear (BN affine computed in-block) -------------

__global__ __launch_bounds__(256) void k_pool(
    const uint* __restrict__ agg, const int* __restrict__ batch,
    const float* __restrict__ cs, const float* __restrict__ gg,
    const float* __restrict__ be,
    const float* __restrict__ Wl, const float* __restrict__ bl,
    float* __restrict__ out) {
    __shared__ float scsh[256];
    int tid = threadIdx.x;
    if (tid < 128) {
        float s = cs[tid], q = cs[128 + tid];
        float m = s * (1.0f / Nn);
        float var = q * (1.0f / Nn) - m * m;
        float istd = rsqrtf(var + EPSb);
        float sc = istd * gg[tid];
        scsh[tid] = sc;
        scsh[128 + tid] = fmaf(-m, sc, be[tid]);
    }
    __syncthreads();
    int lane = tid & 63;
    int g = (blockIdx.x * blockDim.x + tid) >> 6;
    if (g >= Gg) return;
    int lo = 0, hi = Nn;
    while (lo < hi) { int mid = (lo + hi) >> 1; if (batch[mid] < g) lo = mid + 1; else hi = mid; }
    int beg = lo;
    hi = Nn;
    while (lo < hi) { int mid = (lo + hi) >> 1; if (batch[mid] < g + 1) lo = mid + 1; else hi = mid; }
    int end = lo;
    int c0 = lane * 2;
    float sc0 = scsh[c0], sh0 = scsh[128 + c0];
    float sc1 = scsh[c0 + 1], sh1 = scsh[128 + c0 + 1];
    float s0 = 0.f, s1 = 0.f;
    for (int n = beg; n < end; ++n) {
        uint v = agg[(size_t)n * 64 + lane];
        s0 += fmaxf(fmaf(bflo(v), sc0, sh0), 0.f);
        s1 += fmaxf(fmaf(bfhi(v), sc1, sh1), 0.f);
    }
    float inv = 1.0f / fmaxf((float)(end - beg), 1.0f);
    float part = (s0 * inv) * Wl[c0] + (s1 * inv) * Wl[c0 + 1];
#pragma unroll
    for (int off = 32; off; off >>= 1) part += __shfl_down(part, off);
    if (lane == 0) out[g] = part + bl[0];
}

// ---------------- launch --------------------------------------------------

extern "C" void kernel_launch(void* const* d_in, const int* in_sizes, int n_in,
                              void* d_out, int out_size, void* d_ws, size_t ws_size,
                              hipStream_t stream) {
    const float* x   = (const float*)d_in[0];
    const int*   ei  = (const int*)d_in[1];
    const int*   src = ei;
    const int*   dst = ei + Ee;
    const int*   bat = (const int*)d_in[2];
    const float* W1 = (const float*)d_in[3];
    const float* b1 = (const float*)d_in[4];
    const float* g1 = (const float*)d_in[5];
    const float* be1 = (const float*)d_in[6];
    const float* W2 = (const float*)d_in[7];
    const float* b2 = (const float*)d_in[8];
    const float* g2 = (const float*)d_in[9];
    const float* be2 = (const float*)d_in[10];
    const float* W3 = (const float*)d_in[11];
    const float* b3 = (const float*)d_in[12];
    const float* g3 = (const float*)d_in[13];
    const float* be3 = (const float*)d_in[14];
    const float* Wl = (const float*)d_in[15];
    const float* bl = (const float*)d_in[16];
    float* out = (float*)d_out;

    char* w = (char*)d_ws;
    auto alloc = [&](size_t bytes) {
        void* p = (void*)w;
        w += (bytes + 255) & ~(size_t)255;
        return p;
    };
    // deg, bcnt, colsum first and contiguous: one memset zeroes all three
    int*   deg    = (int*)alloc((size_t)Nn * 4);
    int*   bcnt   = (int*)alloc(BKT * 4);
    float* colsum = (float*)alloc(768 * 4);   // 3 layers x 256
    size_t zspan  = (size_t)((char*)(colsum + 768) - (char*)deg);
    int*   offs   = (int*)alloc((size_t)(Nn + 1) * 4);
    float* dinv   = (float*)alloc((size_t)Nn * 4);
    uint*  Wt     = (uint*)alloc((size_t)3 * 8192 * 4);
    uint*  stage  = (uint*)alloc((size_t)BKT * BSTRIDE * 4);   // 9.6 MB
    int*   adj    = (int*)alloc((size_t)Ee * 4);               // src-only, in-edges
    uint*  tmp    = (uint*)alloc((size_t)Nn * 64 * 4);    // bf16-packed h'
    uint*  agg    = (uint*)alloc((size_t)Nn * 64 * 4);    // bf16-packed agg

    float* csA = colsum;        // stats of agg1 (uses g1/be1)
    float* csB = colsum + 256;  // stats of agg2 (uses g2/be2)
    float* csC = colsum + 512;  // stats of agg3 (uses g3/be3)

    // graph preprocessing + weight conversion
    hipMemsetAsync(deg, 0, zspan, stream);
    k_bucket<<<FILL_BLOCKS, 256, 0, stream>>>(src, dst, deg, bcnt, stage);
    k_scan3b<<<BKT, 256, 0, stream>>>(deg, bcnt, offs, dinv);
    k_scatter<<<BKT, 256, 0, stream>>>(bcnt, stage, offs, adj);
    k_wconv3<<<96, 256, 0, stream>>>(W1, W2, W3, Wt);
    // layer 1
    k_gemm<<<GEMM_BLOCKS, 256, 0, stream>>>(x, (const uint*)0, Wt, dinv,
                                            (const float*)0, (const float*)0,
                                            (const float*)0, tmp, 0);
    k_agg<<<AGG_BLOCKS, 256, 0, stream>>>(tmp, offs, adj, dinv, b1, agg, csA);
    // layer 2
    k_gemm<<<GEMM_BLOCKS, 256, 0, stream>>>((const float*)0, agg, Wt + 8192, dinv,
                                            csA, g1, be1, tmp, 1);
    k_agg<<<AGG_BLOCKS, 256, 0, stream>>>(tmp, offs, adj, dinv, b2, agg, csB);
    // layer 3
    k_gemm<<<GEMM_BLOCKS, 256, 0, stream>>>((const float*)0, agg, Wt + 16384, dinv,
                                            csB, g2, be2, tmp, 1);
    k_agg<<<AGG_BLOCKS, 256, 0, stream>>>(tmp, offs, adj, dinv, b3, agg, csC);
    // pool + linear
    k_pool<<<(Gg * 64 + 255) / 256, 256, 0, stream>>>(agg, bat, csC, g3, be3,
                                                      Wl, bl, out);
}